// Round 8
// baseline (21.905 us; speedup 1.0000x reference)
//
#include <hip/hip_runtime.h>
#include <math.h>

#define T_LEN 16384
#define B_ROWS 256
#define BLK 256
#define EPT 16                      // elements per thread
#define COLS (BLK * EPT)            // 4096 columns per block
#define SEG (T_LEN / COLS)          // 4 segments per row
#define GRID (B_ROWS * SEG)         // 1024 blocks
#define NBATCH 4                    // 4 batches of 4 elems per thread
#define BATCH_COLS (COLS / NBATCH)  // 1024 cols per batch
#define BATCH_UNITS (BATCH_COLS/4)  // 256 16B-units per batch
#define WSTRIDE 12                  // floats per block-partial record
#define LDS_UNITS 1028              // 1024 data units + 1 ext + pad

#define LOG2E 1.44269504088896340f
#define LN2   0.69314718055994531f

typedef float v4f __attribute__((ext_vector_type(4)));

// 16B-unit XOR swizzle: keeps dense writes dense, fixes the stride-64B
// cons-phase reads (would be ~32-way conflict linear -> dense-equivalent).
__device__ __forceinline__ int swz(int u) { return u ^ ((u >> 3) & 7); }

__device__ __forceinline__ float fast_sig(float x) {
    float e = __builtin_amdgcn_exp2f(fabsf(x) * -LOG2E);
    float r = __builtin_amdgcn_rcpf(1.0f + e);
    return (x >= 0.f) ? r : e * r;
}

// R8: DENSE loads. R7's tid*EPT layout made each wave load span 4KB / 64
// cache lines (32B used per 128B line) -> TA/L1 request serialization.
// Now thread tid owns cols k*1024 + tid*4 per batch k: each wave load is
// 1KB contiguous. Consistency stencil moves to an LDS pass.

#define LOADK(K, R0, R1, R2, R3)                                  \
    R0 = *(const v4f*)(base_on  + (K) * BATCH_COLS + tc);         \
    R1 = *(const v4f*)(base_off + (K) * BATCH_COLS + tc);         \
    R2 = *(const v4f*)(base_ton + (K) * BATCH_COLS + tc);         \
    R3 = *(const v4f*)(base_tof + (K) * BATCH_COLS + tc);

#define COMPUTE(K, X, Y, TT, UU) {                                            \
    v4f prv, qrv;                                                             \
    _Pragma("unroll")                                                         \
    for (int j = 0; j < 4; j++) {                                             \
        float x = (X)[j], t = (TT)[j];                                        \
        float e = __builtin_amdgcn_exp2f(fabsf(x) * -LOG2E);                  \
        float r = __builtin_amdgcn_rcpf(1.0f + e);                            \
        float sp = fmaf(-LN2, __builtin_amdgcn_logf(r), fmaxf(x, 0.f));       \
        on_sp += sp; on_tsp += t * sp;                                        \
        on_pos += t * fminf(sp - x, 5.0f); on_cnt += t;                       \
        float pr = (x >= 0.f) ? r : e * r; on_psum += pr; prv[j] = pr;        \
        float y = (Y)[j], u = (UU)[j];                                        \
        float e2 = __builtin_amdgcn_exp2f(fabsf(y) * -LOG2E);                 \
        float r2 = __builtin_amdgcn_rcpf(1.0f + e2);                          \
        float sp2 = fmaf(-LN2, __builtin_amdgcn_logf(r2), fmaxf(y, 0.f));     \
        off_sp += sp2; off_tsp += u * sp2;                                    \
        off_pos += u * fminf(sp2 - y, 5.0f); off_cnt += u;                    \
        float qr = (y >= 0.f) ? r2 : e2 * r2; off_psum += qr; qrv[j] = qr;    \
    }                                                                         \
    on_p [swz((K) * BATCH_UNITS + tid)] = prv;                                \
    off_p[swz((K) * BATCH_UNITS + tid)] = qrv; }

__global__ __launch_bounds__(BLK) void loss_partial(
    const float* __restrict__ pon, const float* __restrict__ poff,
    const float* __restrict__ ton, const float* __restrict__ toff,
    float* __restrict__ ws)
{
    const int blk = blockIdx.x;
    const int row = blk >> 2;            // SEG = 4
    const int s   = blk & 3;
    const int tid = threadIdx.x;
    const int C0  = s * COLS;            // segment start (row-local col)
    const int tc  = tid * 4;             // thread's in-batch column
    const size_t rowbase = (size_t)row * T_LEN;

    const float* base_on  = pon  + rowbase + C0;
    const float* base_off = poff + rowbase + C0;
    const float* base_ton = ton  + rowbase + C0;
    const float* base_tof = toff + rowbase + C0;

    __shared__ v4f on_p[LDS_UNITS];      // onset probs (swizzled units)
    __shared__ v4f off_p[LDS_UNITS];     // offset probs
    __shared__ float part[4][9];

    float on_sp = 0.f, on_tsp = 0.f, on_pos = 0.f, on_cnt = 0.f, on_psum = 0.f;
    float off_sp = 0.f, off_tsp = 0.f, off_pos = 0.f, off_cnt = 0.f, off_psum = 0.f;
    float cons = 0.f;

    // ---- ext halo: cols C0+4096..4098 (next block's first 3), slot 3 = 0 ----
    if (tid == 0) {
        float* onf = (float*)on_p;
        float* off_f = (float*)off_p;
        #pragma unroll
        for (int m = 0; m < 4; m++) {
            int g = C0 + COLS + m;
            float pv = 0.f, qv = 0.f;
            if (m < 3 && g < T_LEN) {
                pv = fast_sig(base_on[COLS + m]);
                qv = fast_sig(base_off[COLS + m]);
            }
            onf[4096 + m] = pv;       // swz is identity at unit 1024
            off_f[4096 + m] = qv;
        }
    }

    // ---- depth-2 pipelined stream over 4 dense batches ----
    v4f a0, a1, a2, a3, b0, b1, b2, b3;
    LOADK(0, a0, a1, a2, a3)
    LOADK(1, b0, b1, b2, b3)
    COMPUTE(0, a0, a1, a2, a3)
    LOADK(2, a0, a1, a2, a3)
    COMPUTE(1, b0, b1, b2, b3)
    LOADK(3, b0, b1, b2, b3)
    COMPUTE(2, a0, a1, a2, a3)
    COMPUTE(3, b0, b1, b2, b3)

    __syncthreads();

    // ---- consistency pass from LDS: thread handles jg = C0+tid*16 .. +15 ----
    {
        float onv[20], offv[20];
        #pragma unroll
        for (int a = 0; a < 5; a++) {
            v4f va = on_p [swz(tid * 4 + a)];
            v4f vo = off_p[swz(tid * 4 + a)];
            #pragma unroll
            for (int j = 0; j < 4; j++) {
                onv[a * 4 + j] = va[j];
                offv[a * 4 + j] = vo[j];
            }
        }
        const int g0 = C0 + tid * 16;
        #pragma unroll
        for (int j = 0; j < 16; j++) {
            float rc  = fmaxf(fmaxf(onv[j], onv[j + 1]), onv[j + 2]); // v_max3
            float cur = offv[j + 3];
            bool ok = (g0 + j <= T_LEN - 4) && (rc > 0.5f) && (cur > 0.5f);
            cons += ok ? rc * cur : 0.f;
        }
    }

    // ---- block reduction: 9 partials ----
    float vals[9] = {on_pos, on_sp - on_tsp, on_cnt,
                     off_pos, off_sp - off_tsp, off_cnt,
                     on_psum, off_psum, cons};
    #pragma unroll
    for (int v = 0; v < 9; v++) {
        float a = vals[v];
        for (int o = 32; o > 0; o >>= 1) a += __shfl_down(a, o, 64);
        vals[v] = a;
    }
    const int lane = tid & 63, wid = tid >> 6;
    if (lane == 0) {
        #pragma unroll
        for (int v = 0; v < 9; v++) part[wid][v] = vals[v];
    }
    __syncthreads();
    if (tid < 12) {
        float val = 0.f;
        if (tid < 9) val = part[0][tid] + part[1][tid] + part[2][tid] + part[3][tid];
        ws[(size_t)blk * WSTRIDE + tid] = val;
    }
}

__global__ __launch_bounds__(256) void finalize_k(const float* __restrict__ ws,
                                                  float* __restrict__ out)
{
    const int r = threadIdx.x;   // one row per thread
    float a[9];
    #pragma unroll
    for (int v = 0; v < 9; v++) a[v] = 0.f;
    const float4* p4 = (const float4*)(ws + (size_t)r * SEG * WSTRIDE);
    #pragma unroll
    for (int s = 0; s < SEG; s++) {
        float4 f0 = p4[s * 3 + 0];
        float4 f1 = p4[s * 3 + 1];
        float4 f2 = p4[s * 3 + 2];
        a[0] += f0.x; a[1] += f0.y; a[2] += f0.z; a[3] += f0.w;
        a[4] += f1.x; a[5] += f1.y; a[6] += f1.z; a[7] += f1.w;
        a[8] += f2.x;
    }
    float red[9];
    red[0] = a[0]; red[1] = a[1]; red[2] = a[2];
    red[3] = a[3]; red[4] = a[4]; red[5] = a[5];
    red[6] = a[6];
    red[7] = a[8];
    red[8] = fabsf(a[6] - a[7]);          // per-row |sum_on - sum_off|
    #pragma unroll
    for (int v = 0; v < 9; v++) {
        float x = red[v];
        for (int o = 32; o > 0; o >>= 1) x += __shfl_down(x, o, 64);
        red[v] = x;
    }
    __shared__ float part[4][9];
    const int lane = r & 63, wid = r >> 6;
    if (lane == 0) {
        #pragma unroll
        for (int v = 0; v < 9; v++) part[wid][v] = red[v];
    }
    __syncthreads();
    if (r == 0) {
        float t[9];
        #pragma unroll
        for (int v = 0; v < 9; v++)
            t[v] = part[0][v] + part[1][v] + part[2][v] + part[3][v];
        const float N = (float)B_ROWS * (float)T_LEN;
        float pc = t[2], nc = N - pc;
        float pl = (pc > 0.f) ? t[0] / fmaxf(pc, 1.f) : 0.f;
        float nl = (nc > 0.f) ? t[1] / fmaxf(nc, 1.f) : 0.f;
        float onset_loss = 1.5f * pl + nl;
        float pc2 = t[5], nc2 = N - pc2;
        float pl2 = (pc2 > 0.f) ? t[3] / fmaxf(pc2, 1.f) : 0.f;
        float nl2 = (nc2 > 0.f) ? t[4] / fmaxf(nc2, 1.f) : 0.f;
        float offset_loss = 1.5f * pl2 + nl2;
        float cons_loss = t[7] / ((float)B_ROWS * (float)(T_LEN - 3));
        float pair_loss = t[8] / (float)B_ROWS;
        float mean_on   = t[6] / N;
        float sparsity  = 0.f;   // SPARSE_W == 0
        float total = 5.0f * onset_loss + 3.0f * offset_loss + 0.1f * cons_loss
                    + 0.05f * pair_loss + sparsity;
        out[0] = onset_loss;
        out[1] = offset_loss;
        out[2] = cons_loss;
        out[3] = pair_loss;
        out[4] = sparsity;
        out[5] = mean_on;
        out[6] = total;
    }
}

extern "C" void kernel_launch(void* const* d_in, const int* in_sizes, int n_in,
                              void* d_out, int out_size, void* d_ws, size_t ws_size,
                              hipStream_t stream) {
    const float* pon  = (const float*)d_in[0];
    const float* poff = (const float*)d_in[1];
    const float* ton  = (const float*)d_in[2];
    const float* toff = (const float*)d_in[3];
    float* ws = (float*)d_ws;   // GRID * 12 floats = 49.2 KB
    loss_partial<<<GRID, BLK, 0, stream>>>(pon, poff, ton, toff, ws);
    finalize_k<<<1, BLK, 0, stream>>>(ws, (float*)d_out);
}